// Round 3
// baseline (19801.854 us; speedup 1.0000x reference)
//
#include <hip/hip_runtime.h>
#include <hip/hip_fp16.h>

// LSTM T=1024 B=64 I=H=512.
// Phase 1: xall[t,b, g*512+j] = inputs @ W_xg + b_g   (fp32 SGEMM, f16 store)
// Phase 2: 256 WGs = 16 col-slices (s) x 16 batch-groups (g, 4 b each).
//   Weight slice (128 gate-cols x 512 k, f16, MFMA-frag order) LDS-stationary.
//   Per step: mfma_f32_16x16x32_f16 (M=16 rows, 4 used) -> gates -> h,c update,
//   h exchanged via global hx[t] + per-(t,g,s) flags (agent-scope acq/rel).
// Gate order g: 0=i, 1=f, 2=o, 3=u.

#define TT 1024
#define BB 64
#define II 512
#define HH 512
#define NG 2048
#define NSL 16            // column slices
#define NGR 16            // batch groups
#define BSZ 4             // batch per group
#define HLDS 520          // h_lds row stride in halves (512 + 8 pad)

typedef _Float16 f16x8 __attribute__((ext_vector_type(8)));
typedef float f32x4 __attribute__((ext_vector_type(4)));

__device__ inline float fast_rcp(float x) { return __builtin_amdgcn_rcpf(x); }
__device__ inline float fast_sigmoid(float x) {
  float e = __expf(-x);
  return fast_rcp(1.0f + e);
}
__device__ inline float fast_tanh(float x) {
  float ax = fabsf(x);
  float e = __expf(-2.0f * ax);
  float r = (1.0f - e) * fast_rcp(1.0f + e);
  return copysignf(r, x);
}

// ---------------- prep kernels ----------------

__global__ void prep_bcat(const float* __restrict__ Wxi, const float* __restrict__ Wxf,
                          const float* __restrict__ Wxo, const float* __restrict__ Wxu,
                          float* __restrict__ Bcat) {
  int idx = blockIdx.x * 256 + threadIdx.x;
  int c = idx & (NG - 1), k = idx >> 11;
  int g = c >> 9, j = c & (HH - 1);
  const float* W = (g == 0) ? Wxi : (g == 1) ? Wxf : (g == 2) ? Wxo : Wxu;
  Bcat[idx] = W[k * HH + j];
}

__global__ void prep_bias(const float* __restrict__ bi, const float* __restrict__ bf,
                          const float* __restrict__ bo, const float* __restrict__ bu,
                          float* __restrict__ bias) {
  int c = blockIdx.x * 256 + threadIdx.x;
  int g = c >> 9, j = c & (HH - 1);
  bias[c] = ((g == 0) ? bi : (g == 1) ? bf : (g == 2) ? bo : bu)[j];
}

// Wpk: MFMA B-fragment order. idx = ((s*8 + nt)*16 + kt)*64 + lane.
// lane: col16 = lane&15, kchunk = lane>>4 (8 k-elems). col_in_slice = nt*16+col16,
// gate = cis>>5, jj = cis&31, global col j = s*32+jj, k0 = kt*32 + kchunk*8.
__global__ void prep_wpk(const float* __restrict__ Whi, const float* __restrict__ Whf,
                         const float* __restrict__ Who, const float* __restrict__ Whu,
                         uint4* __restrict__ Wpk) {
  int idx = blockIdx.x * 256 + threadIdx.x;      // 131072 total
  int l = idx & 63, kt = (idx >> 6) & 15, nt = (idx >> 10) & 7, s = idx >> 13;
  int cis = nt * 16 + (l & 15);
  int gate = cis >> 5, jj = cis & 31;
  int cj = s * 32 + jj;
  int k0 = kt * 32 + (l >> 4) * 8;
  const float* W = (gate == 0) ? Whi : (gate == 1) ? Whf : (gate == 2) ? Who : Whu;
  __half p[8];
#pragma unroll
  for (int e = 0; e < 8; ++e) p[e] = __float2half(W[(size_t)(k0 + e) * HH + cj]);
  Wpk[idx] = *(const uint4*)p;
}

// ---------------- phase 1: fp32 SGEMM 128x128 tile, f16 store ----------------

__global__ __launch_bounds__(256, 4)
void sgemm_x(const float* __restrict__ A, const float* __restrict__ Bm,
             const float* __restrict__ bias, __half* __restrict__ Cx) {
  __shared__ float As[8][128];
  __shared__ float Bs[8][128];
  const int tid = threadIdx.x;
  const int r0 = blockIdx.y * 128;
  const int c0 = blockIdx.x * 128;
  const int tx = tid & 15, ty = tid >> 4;

  float acc[8][8];
#pragma unroll
  for (int i = 0; i < 8; ++i)
#pragma unroll
    for (int j = 0; j < 8; ++j) acc[i][j] = 0.f;

  const int arow = tid >> 1;
  const int akq  = (tid & 1) * 4;
  const int bk   = tid >> 5;
  const int bc   = (tid & 31) * 4;

  for (int k0 = 0; k0 < 512; k0 += 8) {
    float4 va = *(const float4*)(A + (size_t)(r0 + arow) * 512 + k0 + akq);
    float4 vb = *(const float4*)(Bm + (size_t)(k0 + bk) * NG + c0 + bc);
    As[akq + 0][arow] = va.x;
    As[akq + 1][arow] = va.y;
    As[akq + 2][arow] = va.z;
    As[akq + 3][arow] = va.w;
    *(float4*)&Bs[bk][bc] = vb;
    __syncthreads();
#pragma unroll
    for (int k = 0; k < 8; ++k) {
      float a[8], b[8];
      *(float4*)&a[0] = *(const float4*)&As[k][ty * 8];
      *(float4*)&a[4] = *(const float4*)&As[k][ty * 8 + 4];
      *(float4*)&b[0] = *(const float4*)&Bs[k][tx * 8];
      *(float4*)&b[4] = *(const float4*)&Bs[k][tx * 8 + 4];
#pragma unroll
      for (int i = 0; i < 8; ++i)
#pragma unroll
        for (int j = 0; j < 8; ++j) acc[i][j] = fmaf(a[i], b[j], acc[i][j]);
    }
    __syncthreads();
  }

  float bsv[8];
  *(float4*)&bsv[0] = *(const float4*)(bias + c0 + tx * 8);
  *(float4*)&bsv[4] = *(const float4*)(bias + c0 + tx * 8 + 4);
#pragma unroll
  for (int i = 0; i < 8; ++i) {
    union { __half h[8]; int4 v; } u;
#pragma unroll
    for (int j = 0; j < 8; ++j) u.h[j] = __float2half(acc[i][j] + bsv[j]);
    *reinterpret_cast<int4*>(Cx + (size_t)(r0 + ty * 8 + i) * NG + c0 + tx * 8) = u.v;
  }
}

// ---------------- phase 2: distributed recurrent scan ----------------

__global__ __launch_bounds__(128, 1)
void lstm_rec(const uint4* __restrict__ Wpk, const __half* __restrict__ xall,
              const float* __restrict__ h_in, const float* __restrict__ c_in,
              float* __restrict__ out, float* __restrict__ h_out,
              float* __restrict__ c_out, __half* __restrict__ hx,
              int* __restrict__ flags, int nsteps, int chunkv) {
  __shared__ uint4 wlds[8192];                 // 128 KiB weight slice (frag order)
  __shared__ __half h_lds[16 * HLDS];          // 16 rows (4 real b + 12 zero)
  __shared__ __align__(16) float gsm[128][4];  // gate pre-acts [col_in_slice][b]
  __shared__ int dead;

  const int wg = blockIdx.x;
  const int s = wg & 15, g = wg >> 4;
  const int tid = threadIdx.x;
  const int l = tid & 63, w = tid >> 6;

  // stage weight slice global->LDS (once)
  const uint4* wsrc = Wpk + (size_t)s * 8192;
  for (int i = tid; i < 8192; i += 128) wlds[i] = wsrc[i];

  // zero h_lds (rows 4..15 stay zero forever)
  for (int i = tid; i < 16 * HLDS; i += 128) h_lds[i] = __float2half(0.f);
  if (tid == 0) dead = 0;

  // per-thread gate-math identity
  const int b_loc = tid >> 5, j = tid & 31;
  const int b_glob = g * BSZ + b_loc;
  float c_reg = c_in[(size_t)b_glob * HH + s * 32 + j];
  float h_reg = 0.f;

  // stage initial h (fp32 -> f16) rows 0..3
  {
    const int r = tid >> 5, part = tid & 31;
    const float* src = h_in + (size_t)(g * BSZ + r) * HH + part * 16;
    __half tmp[16];
#pragma unroll
    for (int e = 0; e < 16; ++e) tmp[e] = __float2half(src[e]);
    *(uint4*)&h_lds[r * HLDS + part * 16] = *(const uint4*)&tmp[0];
    *(uint4*)&h_lds[r * HLDS + part * 16 + 8] = *(const uint4*)&tmp[8];
  }
  __syncthreads();

  const int arow = l & 15;
  const int akoff = (l >> 4) * 8;

  for (int t = 0; t < nsteps; ++t) {
    // x prefetch (independent of h)
    const __half* xb = xall + ((size_t)t * BB + b_glob) * NG + s * 32 + j;
    const float xi = __half2float(xb[0]);
    const float xf = __half2float(xb[512]);
    const float xo = __half2float(xb[1024]);
    const float xu = __half2float(xb[1536]);

    // MFMA: wave w handles N-tiles w*4..w*4+3
    f32x4 acc0 = {0.f, 0.f, 0.f, 0.f}, acc1 = acc0, acc2 = acc0, acc3 = acc0;
#pragma unroll
    for (int kt = 0; kt < 16; ++kt) {
      f16x8 a = *(const f16x8*)&h_lds[arow * HLDS + kt * 32 + akoff];
      f16x8 b0 = __builtin_bit_cast(f16x8, wlds[((w * 4 + 0) * 16 + kt) * 64 + l]);
      f16x8 b1 = __builtin_bit_cast(f16x8, wlds[((w * 4 + 1) * 16 + kt) * 64 + l]);
      f16x8 b2 = __builtin_bit_cast(f16x8, wlds[((w * 4 + 2) * 16 + kt) * 64 + l]);
      f16x8 b3 = __builtin_bit_cast(f16x8, wlds[((w * 4 + 3) * 16 + kt) * 64 + l]);
      acc0 = __builtin_amdgcn_mfma_f32_16x16x32_f16(a, b0, acc0, 0, 0, 0);
      acc1 = __builtin_amdgcn_mfma_f32_16x16x32_f16(a, b1, acc1, 0, 0, 0);
      acc2 = __builtin_amdgcn_mfma_f32_16x16x32_f16(a, b2, acc2, 0, 0, 0);
      acc3 = __builtin_amdgcn_mfma_f32_16x16x32_f16(a, b3, acc3, 0, 0, 0);
    }
    // C/D: col = lane&15, row = (lane>>4)*4 + reg. Rows 0..3 live in lanes 0..15.
    if (l < 16) {
      *(f32x4*)&gsm[(w * 4 + 0) * 16 + l][0] = acc0;
      *(f32x4*)&gsm[(w * 4 + 1) * 16 + l][0] = acc1;
      *(f32x4*)&gsm[(w * 4 + 2) * 16 + l][0] = acc2;
      *(f32x4*)&gsm[(w * 4 + 3) * 16 + l][0] = acc3;
    }
    __syncthreads();

    // gate math: col_in_slice = gate*32 + j
    {
      const float gi = gsm[j][b_loc] + xi;
      const float gf = gsm[32 + j][b_loc] + xf;
      const float go = gsm[64 + j][b_loc] + xo;
      const float gu = gsm[96 + j][b_loc] + xu;
      const float iv = fast_sigmoid(gi);
      const float fv = fast_sigmoid(gf);
      const float ov = fast_sigmoid(go);
      const float uv = fast_tanh(gu);
      c_reg = fv * c_reg + iv * uv;
      h_reg = ov * fast_tanh(c_reg);
      out[((size_t)t * BB + b_glob) * HH + s * 32 + j] = h_reg;
      hx[((size_t)t * BB + b_glob) * HH + s * 32 + j] = __float2half(h_reg);
    }
    __threadfence();
    __syncthreads();
    if (tid == 0)
      __hip_atomic_store(&flags[(t * NGR + g) * NSL + s], chunkv,
                         __ATOMIC_RELEASE, __HIP_MEMORY_SCOPE_AGENT);

    if (t + 1 < nsteps) {
      if (tid < NSL && !dead) {
        const int* f = &flags[(t * NGR + g) * NSL + tid];
        int it = 0;
        while (__hip_atomic_load(f, __ATOMIC_ACQUIRE, __HIP_MEMORY_SCOPE_AGENT) != chunkv) {
          __builtin_amdgcn_s_sleep(2);
          if (++it > (1 << 20)) { dead = 1; break; }   // bail: no hang, absmax will flag
        }
      }
      __syncthreads();
      // restage h rows 0..3 from hx[t]
      const int r = tid >> 5, part = tid & 31;
      const __half* src = hx + ((size_t)t * BB + g * BSZ + r) * HH + part * 16;
      uint4 v0 = *(const uint4*)(src);
      uint4 v1 = *(const uint4*)(src + 8);
      *(uint4*)&h_lds[r * HLDS + part * 16] = v0;
      *(uint4*)&h_lds[r * HLDS + part * 16 + 8] = v1;
      __syncthreads();
    }
  }

  h_out[(size_t)b_glob * HH + s * 32 + j] = h_reg;
  c_out[(size_t)b_glob * HH + s * 32 + j] = c_reg;
}

// ---------------- launch ----------------

extern "C" void kernel_launch(void* const* d_in, const int* in_sizes, int n_in,
                              void* d_out, int out_size, void* d_ws, size_t ws_size,
                              hipStream_t stream) {
  const float* inputs = (const float*)d_in[0];
  const float* h0     = (const float*)d_in[1];
  const float* c0v    = (const float*)d_in[2];
  const float* Wxi    = (const float*)d_in[3];
  const float* Whi    = (const float*)d_in[4];
  const float* Wxf    = (const float*)d_in[5];
  const float* Whf    = (const float*)d_in[6];
  const float* Wxu    = (const float*)d_in[7];
  const float* Whu    = (const float*)d_in[8];
  const float* Wxo    = (const float*)d_in[9];
  const float* Who    = (const float*)d_in[10];
  const float* bi     = (const float*)d_in[11];
  const float* bf     = (const float*)d_in[12];
  const float* bo     = (const float*)d_in[13];
  const float* bu     = (const float*)d_in[14];

  const size_t BCAT_BYTES = (size_t)512 * NG * 4;              // 4 MiB
  const size_t BIAS_BYTES = (size_t)NG * 4;
  const size_t WPK_BYTES  = (size_t)NSL * 8 * 16 * 64 * 16;    // 2 MiB
  const size_t ST_BYTES   = (size_t)BB * HH * 4;               // 128 KiB
  const size_t FIXED      = BCAT_BYTES + BIAS_BYTES + WPK_BYTES + 2 * ST_BYTES;
  // per timestep: xall f16 (64*2048*2) + hx f16 (64*512*2) + flags (16*16*4)
  const size_t PER_T = (size_t)BB * NG * 2 + (size_t)BB * HH * 2 + NGR * NSL * 4;

  int TCH = TT;
  while (TCH > 8 && FIXED + (size_t)TCH * PER_T > ws_size) TCH >>= 1;

  char* ws = (char*)d_ws;
  float*  Bcat    = (float*)ws;
  float*  bias    = (float*)(ws + BCAT_BYTES);
  uint4*  Wpk     = (uint4*)(ws + BCAT_BYTES + BIAS_BYTES);
  float*  h_state = (float*)(ws + BCAT_BYTES + BIAS_BYTES + WPK_BYTES);
  float*  c_state = (float*)(ws + BCAT_BYTES + BIAS_BYTES + WPK_BYTES + ST_BYTES);
  char*   dyn     = ws + FIXED;
  __half* xall    = (__half*)dyn;
  __half* hx      = (__half*)(dyn + (size_t)TCH * BB * NG * 2);
  int*    flags   = (int*)(dyn + (size_t)TCH * BB * NG * 2 + (size_t)TCH * BB * HH * 2);

  float* out = (float*)d_out;
  float* hT  = out + (size_t)TT * BB * HH;
  float* cT  = hT + (size_t)BB * HH;

  prep_bcat<<<(512 * NG) / 256, 256, 0, stream>>>(Wxi, Wxf, Wxo, Wxu, Bcat);
  prep_bias<<<NG / 256, 256, 0, stream>>>(bi, bf, bo, bu, bias);
  prep_wpk<<<(NSL * 8 * 16 * 64) / 256, 256, 0, stream>>>(Whi, Whf, Who, Whu, Wpk);

  const int nch = TT / TCH;
  for (int ch = 0; ch < nch; ++ch) {
    const int t0 = ch * TCH;
    sgemm_x<<<dim3(NG / 128, (TCH * BB) / 128), 256, 0, stream>>>(
        inputs + (size_t)t0 * BB * II, Bcat, bias, xall);
    const float* hin = (ch == 0) ? h0 : h_state;
    const float* cin = (ch == 0) ? c0v : c_state;
    float* hout = (ch == nch - 1) ? hT : h_state;
    float* cout = (ch == nch - 1) ? cT : c_state;
    lstm_rec<<<NSL * NGR, 128, 0, stream>>>(Wpk, xall, hin, cin,
                                            out + (size_t)t0 * BB * HH, hout, cout,
                                            hx, flags, TCH, ch + 1);
  }
}

// Round 5
// 6352.924 us; speedup vs baseline: 3.1170x; 3.1170x over previous
//
#include <hip/hip_runtime.h>
#include <hip/hip_fp16.h>

// LSTM T=1024 B=64 I=H=512.
// Phase 1: xall[t,b, g*512+j] = inputs @ W_xg + b_g   (fp32 SGEMM, f16 store)
// Phase 2: 256 WGs = 16 col-slices (s) x 16 batch-groups (g, 4 b each).
//   Weight slice (128 gate-cols x 512 k, f16, MFMA B-frag order) REGISTER-
//   stationary (~256 VGPR/wave). Per step: mfma_f32_16x16x32_f16 -> gates ->
//   h,c update; h exchanged via LLC-resident relaxed agent atomics
//   (hx double-buffered by t parity) + per-(t,g) arrival counter.
//   x loads for step t+1 are issued before the step-t poll (latency hiding).
//   wg = s*16+g so a group's 16 WGs share an XCD under round-robin dispatch
//   (perf heuristic only; correctness relies on agent-scope atomics).
// Gate order: 0=i, 1=f, 2=o, 3=u.

#define TT 1024
#define BB 64
#define II 512
#define HH 512
#define NG 2048
#define NSL 16            // column slices
#define NGR 16            // batch groups
#define BSZ 4             // batch per group
#define HLDS 520          // h_lds row stride in halves (512 + 8 pad)

typedef _Float16 f16x8 __attribute__((ext_vector_type(8)));
typedef float f32x4 __attribute__((ext_vector_type(4)));

__device__ inline float fast_rcp(float x) { return __builtin_amdgcn_rcpf(x); }
__device__ inline float fast_sigmoid(float x) {
  float e = __expf(-x);
  return fast_rcp(1.0f + e);
}
__device__ inline float fast_tanh(float x) {
  float ax = fabsf(x);
  float e = __expf(-2.0f * ax);
  float r = (1.0f - e) * fast_rcp(1.0f + e);
  return copysignf(r, x);
}

// ---------------- prep kernels ----------------

__global__ void prep_bcat(const float* __restrict__ Wxi, const float* __restrict__ Wxf,
                          const float* __restrict__ Wxo, const float* __restrict__ Wxu,
                          float* __restrict__ Bcat) {
  int idx = blockIdx.x * 256 + threadIdx.x;
  int c = idx & (NG - 1), k = idx >> 11;
  int g = c >> 9, j = c & (HH - 1);
  const float* W = (g == 0) ? Wxi : (g == 1) ? Wxf : (g == 2) ? Wxo : Wxu;
  Bcat[idx] = W[k * HH + j];
}

__global__ void prep_bias(const float* __restrict__ bi, const float* __restrict__ bf,
                          const float* __restrict__ bo, const float* __restrict__ bu,
                          float* __restrict__ bias) {
  int c = blockIdx.x * 256 + threadIdx.x;
  int g = c >> 9, j = c & (HH - 1);
  bias[c] = ((g == 0) ? bi : (g == 1) ? bf : (g == 2) ? bo : bu)[j];
}

// Wpk: MFMA B-fragment order. idx = ((s*8 + nt)*16 + kt)*64 + lane.
// lane: col16 = lane&15, kchunk = lane>>4 (8 k-elems). col_in_slice = nt*16+col16,
// gate = cis>>5, jj = cis&31, global col j = s*32+jj, k0 = kt*32 + kchunk*8.
__global__ void prep_wpk(const float* __restrict__ Whi, const float* __restrict__ Whf,
                         const float* __restrict__ Who, const float* __restrict__ Whu,
                         uint4* __restrict__ Wpk) {
  int idx = blockIdx.x * 256 + threadIdx.x;      // 131072 total
  int l = idx & 63, kt = (idx >> 6) & 15, nt = (idx >> 10) & 7, s = idx >> 13;
  int cis = nt * 16 + (l & 15);
  int gate = cis >> 5, jj = cis & 31;
  int cj = s * 32 + jj;
  int k0 = kt * 32 + (l >> 4) * 8;
  const float* W = (gate == 0) ? Whi : (gate == 1) ? Whf : (gate == 2) ? Who : Whu;
  __half p[8];
#pragma unroll
  for (int e = 0; e < 8; ++e) p[e] = __float2half(W[(size_t)(k0 + e) * HH + cj]);
  Wpk[idx] = *(const uint4*)p;
}

__global__ void zero_cnt(int* __restrict__ p, int n) {
  int i = blockIdx.x * 256 + threadIdx.x;
  if (i < n) p[i] = 0;
}

// ---------------- phase 1: fp32 SGEMM 128x128 tile, f16 store ----------------

__global__ __launch_bounds__(256, 4)
void sgemm_x(const float* __restrict__ A, const float* __restrict__ Bm,
             const float* __restrict__ bias, __half* __restrict__ Cx) {
  __shared__ float As[8][128];
  __shared__ float Bs[8][128];
  const int tid = threadIdx.x;
  const int r0 = blockIdx.y * 128;
  const int c0 = blockIdx.x * 128;
  const int tx = tid & 15, ty = tid >> 4;

  float acc[8][8];
#pragma unroll
  for (int i = 0; i < 8; ++i)
#pragma unroll
    for (int j = 0; j < 8; ++j) acc[i][j] = 0.f;

  const int arow = tid >> 1;
  const int akq  = (tid & 1) * 4;
  const int bk   = tid >> 5;
  const int bc   = (tid & 31) * 4;

  for (int k0 = 0; k0 < 512; k0 += 8) {
    float4 va = *(const float4*)(A + (size_t)(r0 + arow) * 512 + k0 + akq);
    float4 vb = *(const float4*)(Bm + (size_t)(k0 + bk) * NG + c0 + bc);
    As[akq + 0][arow] = va.x;
    As[akq + 1][arow] = va.y;
    As[akq + 2][arow] = va.z;
    As[akq + 3][arow] = va.w;
    *(float4*)&Bs[bk][bc] = vb;
    __syncthreads();
#pragma unroll
    for (int k = 0; k < 8; ++k) {
      float a[8], b[8];
      *(float4*)&a[0] = *(const float4*)&As[k][ty * 8];
      *(float4*)&a[4] = *(const float4*)&As[k][ty * 8 + 4];
      *(float4*)&b[0] = *(const float4*)&Bs[k][tx * 8];
      *(float4*)&b[4] = *(const float4*)&Bs[k][tx * 8 + 4];
#pragma unroll
      for (int i = 0; i < 8; ++i)
#pragma unroll
        for (int j = 0; j < 8; ++j) acc[i][j] = fmaf(a[i], b[j], acc[i][j]);
    }
    __syncthreads();
  }

  float bsv[8];
  *(float4*)&bsv[0] = *(const float4*)(bias + c0 + tx * 8);
  *(float4*)&bsv[4] = *(const float4*)(bias + c0 + tx * 8 + 4);
#pragma unroll
  for (int i = 0; i < 8; ++i) {
    union { __half h[8]; int4 v; } u;
#pragma unroll
    for (int j = 0; j < 8; ++j) u.h[j] = __float2half(acc[i][j] + bsv[j]);
    *reinterpret_cast<int4*>(Cx + (size_t)(r0 + ty * 8 + i) * NG + c0 + tx * 8) = u.v;
  }
}

// ---------------- phase 2: distributed recurrent scan ----------------

__global__ __launch_bounds__(128, 1)
void lstm_rec(const uint4* __restrict__ Wpk, const __half* __restrict__ xall,
              const float* __restrict__ h_in, const float* __restrict__ c_in,
              float* __restrict__ out, float* __restrict__ h_out,
              float* __restrict__ c_out, unsigned* __restrict__ hx,
              int* __restrict__ cnt, int nsteps, int chunkv) {
  __shared__ __half h_lds[16 * HLDS];          // 16 rows (4 real b + 12 zero)
  __shared__ __align__(16) float gsm[128][4];  // gate pre-acts [col_in_slice][b]
  __shared__ unsigned hnew[64];                // packed new h for our slice [b][16]
  __shared__ int dead;

  const int wg = blockIdx.x;
  const int g = wg & (NGR - 1);                // wg = s*16+g -> group g on XCD g%8
  const int s = wg >> 4;
  const int tid = threadIdx.x;
  const int l = tid & 63, w = tid >> 6;

  // ---- stage weight B-fragments into registers (256 VGPR/wave) ----
  f16x8 wb0[16], wb1[16], wb2[16], wb3[16];
  {
    const uint4* wsrc = Wpk + (((size_t)s * 8 + w * 4) * 16) * 64 + l;
#pragma unroll
    for (int kt = 0; kt < 16; ++kt) {
      wb0[kt] = __builtin_bit_cast(f16x8, wsrc[(0 * 16 + kt) * 64]);
      wb1[kt] = __builtin_bit_cast(f16x8, wsrc[(1 * 16 + kt) * 64]);
      wb2[kt] = __builtin_bit_cast(f16x8, wsrc[(2 * 16 + kt) * 64]);
      wb3[kt] = __builtin_bit_cast(f16x8, wsrc[(3 * 16 + kt) * 64]);
    }
  }

  for (int i = tid; i < 16 * HLDS; i += 128) h_lds[i] = __float2half(0.f);
  if (tid == 0) dead = 0;

  const int b_loc = tid >> 5, j = tid & 31;
  const int b_glob = g * BSZ + b_loc;
  float c_reg = c_in[(size_t)b_glob * HH + s * 32 + j];
  float h_reg = 0.f;

  // stage initial h (fp32 -> f16) rows 0..3
  {
    const int r = tid >> 5, part = tid & 31;
    const float* src = h_in + (size_t)(g * BSZ + r) * HH + part * 16;
    __half tmp[16];
#pragma unroll
    for (int e = 0; e < 16; ++e) tmp[e] = __float2half(src[e]);
    *(uint4*)&h_lds[r * HLDS + part * 16] = *(const uint4*)&tmp[0];
    *(uint4*)&h_lds[r * HLDS + part * 16 + 8] = *(const uint4*)&tmp[8];
  }
  __syncthreads();

  const int arow = l & 15;
  const int akoff = (l >> 4) * 8;

  // x for step 0 (prefetched; subsequent steps prefetch during the poll)
  const __half* xb0 = xall + ((size_t)b_glob) * NG + s * 32 + j;
  __half rxi = xb0[0], rxf = xb0[512], rxo = xb0[1024], rxu = xb0[1536];

  for (int t = 0; t < nsteps; ++t) {
    f32x4 acc0 = {0.f, 0.f, 0.f, 0.f}, acc1 = acc0, acc2 = acc0, acc3 = acc0;
#pragma unroll
    for (int kt = 0; kt < 16; ++kt) {
      f16x8 a = *(const f16x8*)&h_lds[arow * HLDS + kt * 32 + akoff];
      acc0 = __builtin_amdgcn_mfma_f32_16x16x32_f16(a, wb0[kt], acc0, 0, 0, 0);
      acc1 = __builtin_amdgcn_mfma_f32_16x16x32_f16(a, wb1[kt], acc1, 0, 0, 0);
      acc2 = __builtin_amdgcn_mfma_f32_16x16x32_f16(a, wb2[kt], acc2, 0, 0, 0);
      acc3 = __builtin_amdgcn_mfma_f32_16x16x32_f16(a, wb3[kt], acc3, 0, 0, 0);
    }
    // C/D: col = lane&15, row = (lane>>4)*4 + reg. Rows 0..3 live in lanes 0..15.
    if (l < 16) {
      *(f32x4*)&gsm[(w * 4 + 0) * 16 + l][0] = acc0;
      *(f32x4*)&gsm[(w * 4 + 1) * 16 + l][0] = acc1;
      *(f32x4*)&gsm[(w * 4 + 2) * 16 + l][0] = acc2;
      *(f32x4*)&gsm[(w * 4 + 3) * 16 + l][0] = acc3;
    }
    __syncthreads();

    // gate math: col_in_slice = gate*32 + j
    {
      const float gi = gsm[j][b_loc] + __half2float(rxi);
      const float gf = gsm[32 + j][b_loc] + __half2float(rxf);
      const float go = gsm[64 + j][b_loc] + __half2float(rxo);
      const float gu = gsm[96 + j][b_loc] + __half2float(rxu);
      const float iv = fast_sigmoid(gi);
      const float fv = fast_sigmoid(gf);
      const float ov = fast_sigmoid(go);
      const float uv = fast_tanh(gu);
      c_reg = fv * c_reg + iv * uv;
      h_reg = ov * fast_tanh(c_reg);
      ((__half*)hnew)[b_loc * 32 + j] = __float2half(h_reg);
    }
    __syncthreads();

    // publish our slice of h_{t+1} to LLC (wave 0 only), then bump counter
    const int slot = (t + 1) & 1;
    if (tid < 64) {
      unsigned v = hnew[tid];                  // [b][d], b = tid>>4, d = tid&15
      const int db = (g * BSZ + (tid >> 4)) * 256 + s * 16 + (tid & 15);
      __hip_atomic_store(&hx[slot * 16384 + db], v,
                         __ATOMIC_RELAXED, __HIP_MEMORY_SCOPE_AGENT);
    }
    asm volatile("s_waitcnt vmcnt(0)" ::: "memory");
    if (tid == 0)
      __hip_atomic_fetch_add(&cnt[t * NGR + g], 1,
                             __ATOMIC_RELAXED, __HIP_MEMORY_SCOPE_AGENT);

    // result write (off the critical path)
    out[((size_t)t * BB + b_glob) * HH + s * 32 + j] = h_reg;

    if (t + 1 < nsteps) {
      // prefetch x(t+1): issues before the poll, completes under it
      const __half* xb = xall + ((size_t)(t + 1) * BB + b_glob) * NG + s * 32 + j;
      rxi = xb[0]; rxf = xb[512]; rxo = xb[1024]; rxu = xb[1536];

      if (tid == 0 && !dead) {
        // accumulated counter: after chunk chunkv, value = 16*chunkv
        int it = 0;
        while (__hip_atomic_load(&cnt[t * NGR + g], __ATOMIC_RELAXED,
                                 __HIP_MEMORY_SCOPE_AGENT) < NSL * chunkv) {
          __builtin_amdgcn_s_sleep(1);
          if (++it > (1 << 22)) { dead = 1; break; }   // bail: no hang
        }
      }
      __syncthreads();
      // restage h rows 0..3 from hx slot
      const unsigned* src = hx + slot * 16384 + g * BSZ * 256;
#pragma unroll
      for (int i = 0; i < 8; ++i) {
        const int id = i * 128 + tid;          // 0..1023 dwords
        unsigned v = __hip_atomic_load(&src[id], __ATOMIC_RELAXED,
                                       __HIP_MEMORY_SCOPE_AGENT);
        const int r = id >> 8, c = id & 255;
        *(unsigned*)&h_lds[r * HLDS + 2 * c] = v;
      }
      __syncthreads();
    }
  }

  h_out[(size_t)b_glob * HH + s * 32 + j] = h_reg;
  c_out[(size_t)b_glob * HH + s * 32 + j] = c_reg;
}

// ---------------- launch ----------------

extern "C" void kernel_launch(void* const* d_in, const int* in_sizes, int n_in,
                              void* d_out, int out_size, void* d_ws, size_t ws_size,
                              hipStream_t stream) {
  const float* inputs = (const float*)d_in[0];
  const float* h0     = (const float*)d_in[1];
  const float* c0v    = (const float*)d_in[2];
  const float* Wxi    = (const float*)d_in[3];
  const float* Whi    = (const float*)d_in[4];
  const float* Wxf    = (const float*)d_in[5];
  const float* Whf    = (const float*)d_in[6];
  const float* Wxu    = (const float*)d_in[7];
  const float* Whu    = (const float*)d_in[8];
  const float* Wxo    = (const float*)d_in[9];
  const float* Who    = (const float*)d_in[10];
  const float* bi     = (const float*)d_in[11];
  const float* bf     = (const float*)d_in[12];
  const float* bo     = (const float*)d_in[13];
  const float* bu     = (const float*)d_in[14];

  const size_t BCAT_BYTES = (size_t)512 * NG * 4;              // 4 MiB
  const size_t BIAS_BYTES = (size_t)NG * 4;
  const size_t WPK_BYTES  = (size_t)NSL * 8 * 16 * 64 * 16;    // 2 MiB
  const size_t ST_BYTES   = (size_t)BB * HH * 4;               // 128 KiB
  const size_t HX_BYTES   = (size_t)2 * BB * 256 * 4;          // 128 KiB
  const size_t CNT_BYTES  = (size_t)TT * NGR * 4;              // 64 KiB
  const size_t FIXED = BCAT_BYTES + BIAS_BYTES + WPK_BYTES + 2 * ST_BYTES +
                       HX_BYTES + CNT_BYTES;
  const size_t PER_T = (size_t)BB * NG * 2;                    // xall f16

  int TCH = TT;
  while (TCH > 8 && FIXED + (size_t)TCH * PER_T > ws_size) TCH >>= 1;

  char* ws = (char*)d_ws;
  float*    Bcat    = (float*)ws;
  float*    bias    = (float*)(ws + BCAT_BYTES);
  uint4*    Wpk     = (uint4*)(ws + BCAT_BYTES + BIAS_BYTES);
  float*    h_state = (float*)(ws + BCAT_BYTES + BIAS_BYTES + WPK_BYTES);
  float*    c_state = (float*)(ws + BCAT_BYTES + BIAS_BYTES + WPK_BYTES + ST_BYTES);
  unsigned* hx      = (unsigned*)(ws + BCAT_BYTES + BIAS_BYTES + WPK_BYTES + 2 * ST_BYTES);
  int*      cnt     = (int*)(ws + BCAT_BYTES + BIAS_BYTES + WPK_BYTES + 2 * ST_BYTES + HX_BYTES);
  __half*   xall    = (__half*)(ws + FIXED);

  float* out = (float*)d_out;
  float* hT  = out + (size_t)TT * BB * HH;
  float* cT  = hT + (size_t)BB * HH;

  prep_bcat<<<(512 * NG) / 256, 256, 0, stream>>>(Wxi, Wxf, Wxo, Wxu, Bcat);
  prep_bias<<<NG / 256, 256, 0, stream>>>(bi, bf, bo, bu, bias);
  prep_wpk<<<(NSL * 8 * 16 * 64) / 256, 256, 0, stream>>>(Whi, Whf, Who, Whu, Wpk);
  zero_cnt<<<(TT * NGR + 255) / 256, 256, 0, stream>>>(cnt, TT * NGR);

  const int nch = TT / TCH;
  for (int ch = 0; ch < nch; ++ch) {
    const int t0 = ch * TCH;
    sgemm_x<<<dim3(NG / 128, (TCH * BB) / 128), 256, 0, stream>>>(
        inputs + (size_t)t0 * BB * II, Bcat, bias, xall);
    const float* hin = (ch == 0) ? h0 : h_state;
    const float* cin = (ch == 0) ? c0v : c_state;
    float* hout = (ch == nch - 1) ? hT : h_state;
    float* cout = (ch == nch - 1) ? cT : c_state;
    lstm_rec<<<NSL * NGR, 128, 0, stream>>>(Wpk, xall, hin, cin,
                                            out + (size_t)t0 * BB * HH, hout, cout,
                                            hx, cnt, TCH, ch + 1);
  }
}

// Round 8
// 3882.995 us; speedup vs baseline: 5.0996x; 1.6361x over previous
//
#include <hip/hip_runtime.h>
#include <hip/hip_fp16.h>

// LSTM T=1024 B=64 I=H=512.
// Phase 1: xall = inputs @ [W_xi|W_xf|W_xo|W_xu] + bias, f16 MFMA GEMM,
//          A/B pre-packed in MFMA fragment order, no LDS.
// Phase 2: 256 WGs = 16 col-slices (s) x 16 batch-groups (g, 4 b each).
//   Weight slice (128 gate-cols x 512 k, f16, frag order) LDS-stationary
//   (128 KiB). Per step: mfma_f32_16x16x32_f16 -> gates -> h,c update.
//   h exchange: tagged-dword protocol — each h element published as one
//   relaxed agent-scope atomic dword (tag16<<16 | f16), readers poll for
//   tag match. No fences, no atomic RMWs, no shared counters. Parity
//   double-buffered hx. x(t+1) prefetched before the poll so HBM/L2
//   latency hides under the spin. Bounded spin -> no hang.
//   h_frag LDS layout [kt][q][row][8] -> lane-linear ds_read_b128 (no bank
//   conflicts; the [kt][row][q] variant was an 8-way conflict).
// Gate order: 0=i, 1=f, 2=o, 3=u.  (inputs order: W_xu before W_xo!)

#define TT 1024
#define BB 64
#define II 512
#define HH 512
#define NG 2048
#define NSL 16
#define NGR 16
#define BSZ 4

typedef _Float16 f16x8 __attribute__((ext_vector_type(8)));
typedef float f32x4 __attribute__((ext_vector_type(4)));

__device__ inline float fast_rcp(float x) { return __builtin_amdgcn_rcpf(x); }
__device__ inline float fast_sigmoid(float x) {
  float e = __expf(-x);
  return fast_rcp(1.0f + e);
}
__device__ inline float fast_tanh(float x) {
  float ax = fabsf(x);
  float e = __expf(-2.0f * ax);
  float r = (1.0f - e) * fast_rcp(1.0f + e);
  return copysignf(r, x);
}

// ---------------- prep kernels ----------------

__global__ void prep_bias(const float* __restrict__ bi, const float* __restrict__ bf,
                          const float* __restrict__ bo, const float* __restrict__ bu,
                          float* __restrict__ bias) {
  int c = blockIdx.x * 256 + threadIdx.x;
  int g = c >> 9, j = c & (HH - 1);
  bias[c] = ((g == 0) ? bi : (g == 1) ? bf : (g == 2) ? bo : bu)[j];
}

// Wpk (recurrent weights, per-slice gate-interleaved frag order):
// idx = ((s*8 + nt)*16 + kt)*64 + l; cis = nt*16+(l&15); gate=cis>>5; jj=cis&31;
// col = s*32+jj; k0 = kt*32 + (l>>4)*8.
__global__ void prep_wpk(const float* __restrict__ Whi, const float* __restrict__ Whf,
                         const float* __restrict__ Who, const float* __restrict__ Whu,
                         uint4* __restrict__ Wpk) {
  int idx = blockIdx.x * 256 + threadIdx.x;      // 131072
  int l = idx & 63, kt = (idx >> 6) & 15, nt = (idx >> 10) & 7, s = idx >> 13;
  int cis = nt * 16 + (l & 15);
  int gate = cis >> 5, jj = cis & 31;
  int cj = s * 32 + jj;
  int k0 = kt * 32 + (l >> 4) * 8;
  const float* W = (gate == 0) ? Whi : (gate == 1) ? Whf : (gate == 2) ? Who : Whu;
  __half p[8];
#pragma unroll
  for (int e = 0; e < 8; ++e) p[e] = __float2half(W[(size_t)(k0 + e) * HH + cj]);
  Wpk[idx] = *(const uint4*)p;
}

// Wxpk (input weights, col-linear frag order over 2048 cols):
// idx = (ct*16 + kt)*64 + l; ct 0..127; col = ct*16 + (l&15) (gate = ct>>5);
__global__ void prep_wxpk(const float* __restrict__ Wxi, const float* __restrict__ Wxf,
                          const float* __restrict__ Wxo, const float* __restrict__ Wxu,
                          uint4* __restrict__ Wxpk) {
  int idx = blockIdx.x * 256 + threadIdx.x;      // 131072
  int l = idx & 63, kt = (idx >> 6) & 15, ct = idx >> 10;
  int gate = ct >> 5;
  int jj = (ct & 31) * 16 + (l & 15);
  int k0 = kt * 32 + (l >> 4) * 8;
  const float* W = (gate == 0) ? Wxi : (gate == 1) ? Wxf : (gate == 2) ? Wxo : Wxu;
  __half p[8];
#pragma unroll
  for (int e = 0; e < 8; ++e) p[e] = __float2half(W[(size_t)(k0 + e) * HH + jj]);
  Wxpk[idx] = *(const uint4*)p;
}

// Axpk: inputs rows -> f16 A-frag order. thread = row*64 + k8.
__global__ void prep_axpk(const float* __restrict__ A, uint4* __restrict__ Axpk) {
  int idx = blockIdx.x * 256 + threadIdx.x;
  int row = idx >> 6, k8 = idx & 63;
  int kt = k8 >> 2, q = k8 & 3;
  int l = q * 16 + (row & 15);
  const float* src = A + (size_t)row * II + k8 * 8;
  float4 v0 = *(const float4*)src;
  float4 v1 = *(const float4*)(src + 4);
  __half p[8];
  p[0] = __float2half(v0.x); p[1] = __float2half(v0.y);
  p[2] = __float2half(v0.z); p[3] = __float2half(v0.w);
  p[4] = __float2half(v1.x); p[5] = __float2half(v1.y);
  p[6] = __float2half(v1.z); p[7] = __float2half(v1.w);
  Axpk[((size_t)(row >> 4) * 16 + kt) * 64 + l] = *(const uint4*)p;
}

// ---------------- phase 1: f16 MFMA GEMM, no LDS ----------------
// Each wave: 64x64 tile. wid = blockIdx*4+w; m_idx = wid & (2^mshift-1),
// n_idx = wid >> mshift (n64 count = 32).

__global__ __launch_bounds__(256)
void gemm_x(const uint4* __restrict__ Axpk, const uint4* __restrict__ Wxpk,
            const float* __restrict__ bias, __half* __restrict__ Cx, int mshift) {
  const int w = threadIdx.x >> 6, l = threadIdx.x & 63;
  const int wid = blockIdx.x * 4 + w;
  const int m_idx = wid & ((1 << mshift) - 1);
  const int n_idx = wid >> mshift;
  const size_t aBase = (size_t)m_idx * 4096 + l;
  const size_t bBase = (size_t)n_idx * 4096 + l;

  f32x4 acc[4][4];
#pragma unroll
  for (int mi = 0; mi < 4; ++mi)
#pragma unroll
    for (int ni = 0; ni < 4; ++ni) acc[mi][ni] = (f32x4){0.f, 0.f, 0.f, 0.f};

#pragma unroll 2
  for (int kt = 0; kt < 16; ++kt) {
    f16x8 a[4], b[4];
#pragma unroll
    for (int mi = 0; mi < 4; ++mi)
      a[mi] = __builtin_bit_cast(f16x8, Axpk[aBase + mi * 1024 + kt * 64]);
#pragma unroll
    for (int ni = 0; ni < 4; ++ni)
      b[ni] = __builtin_bit_cast(f16x8, Wxpk[bBase + ni * 1024 + kt * 64]);
#pragma unroll
    for (int mi = 0; mi < 4; ++mi)
#pragma unroll
      for (int ni = 0; ni < 4; ++ni)
        acc[mi][ni] = __builtin_amdgcn_mfma_f32_16x16x32_f16(a[mi], b[ni], acc[mi][ni], 0, 0, 0);
  }

  const int col0 = n_idx * 64 + (l & 15);
  float bv[4];
#pragma unroll
  for (int ni = 0; ni < 4; ++ni) bv[ni] = bias[col0 + ni * 16];
  const int row0 = m_idx * 64 + (l >> 4) * 4;
#pragma unroll
  for (int mi = 0; mi < 4; ++mi)
#pragma unroll
    for (int ni = 0; ni < 4; ++ni)
#pragma unroll
      for (int r = 0; r < 4; ++r)
        Cx[(size_t)(row0 + mi * 16 + r) * NG + col0 + ni * 16] =
            __float2half(acc[mi][ni][r] + bv[ni]);
}

// ---------------- phase 2: distributed recurrent scan ----------------

__global__ __launch_bounds__(128, 1)
void lstm_rec(const uint4* __restrict__ Wpk, const __half* __restrict__ xall,
              const float* __restrict__ h_in, const float* __restrict__ c_in,
              float* __restrict__ out, float* __restrict__ h_out,
              float* __restrict__ c_out, unsigned* __restrict__ hx,
              int nsteps, int tbase) {
  __shared__ __half wlds[65536];        // 128 KiB weight slice, frag order
  __shared__ __half h_frag[8192];       // 16 KiB: [kt16][q4][row16][8] halves
  __shared__ float gsm[4][132];         // gate pre-acts [b][cis], padded
  volatile __shared__ int dead;

  const int wg = blockIdx.x;
  const int g = wg & (NGR - 1);         // wg = s*16+g (group on one XCD heur.)
  const int s = wg >> 4;
  const int tid = threadIdx.x;
  const int l = tid & 63, w = tid >> 6;

  // stage weight slice -> LDS (once per chunk)
  {
    const uint4* wsrc = Wpk + (size_t)s * 8192;
    uint4* wd = (uint4*)wlds;
    for (int i = tid; i < 8192; i += 128) wd[i] = wsrc[i];
  }
  for (int i = tid; i < 8192; i += 128) h_frag[i] = __float2half(0.f);
  if (tid == 0) dead = 0;
  __syncthreads();

  // restage identity: thread covers h[r5][w5*16 .. w5*16+15]
  // h_frag off: kt = w5>>1, q0 = (w5&1)*2; halves at kt*512 + q*128 + r5*8
  const int r5 = tid >> 5, w5 = tid & 31;
  const int hoff = (w5 >> 1) * 512 + (w5 & 1) * 256 + r5 * 8;  // q0 part
  // second 8 halves at hoff + 128 (q0+1)

  // stage initial h rows 0..3 (fp32 -> f16, frag layout)
  {
    const float* src = h_in + (size_t)(g * BSZ + r5) * HH + w5 * 16;
    __half tmp[16];
#pragma unroll
    for (int e = 0; e < 16; ++e) tmp[e] = __float2half(src[e]);
    *(uint4*)&h_frag[hoff] = *(const uint4*)&tmp[0];
    *(uint4*)&h_frag[hoff + 128] = *(const uint4*)&tmp[8];
  }

  const int b_loc = tid >> 5, j = tid & 31;     // gate-math identity
  const int b_glob = g * BSZ + b_loc;
  float c_reg = c_in[(size_t)b_glob * HH + s * 32 + j];
  float h_reg = 0.f;
  __syncthreads();

  const int arow = l & 15, aq = l >> 4;
  // A-read: h_frag[kt*512 + aq*128 + arow*8] -> lane-linear bytes (no conflict)

  // prefetch x for t=0
  const __half* xb0 = xall + ((size_t)b_glob) * NG + s * 32 + j;
  __half rxi = xb0[0], rxf = xb0[512], rxo = xb0[1024], rxu = xb0[1536];

  for (int t = 0; t < nsteps; ++t) {
    f32x4 acc0 = {0.f, 0.f, 0.f, 0.f}, acc1 = acc0, acc2 = acc0, acc3 = acc0;
#pragma unroll
    for (int kt = 0; kt < 16; ++kt) {
      f16x8 a = *(const f16x8*)&h_frag[kt * 512 + aq * 128 + arow * 8];
      f16x8 b0 = *(const f16x8*)&wlds[(((w * 4 + 0) * 16 + kt) * 64 + l) * 8];
      f16x8 b1 = *(const f16x8*)&wlds[(((w * 4 + 1) * 16 + kt) * 64 + l) * 8];
      f16x8 b2 = *(const f16x8*)&wlds[(((w * 4 + 2) * 16 + kt) * 64 + l) * 8];
      f16x8 b3 = *(const f16x8*)&wlds[(((w * 4 + 3) * 16 + kt) * 64 + l) * 8];
      acc0 = __builtin_amdgcn_mfma_f32_16x16x32_f16(a, b0, acc0, 0, 0, 0);
      acc1 = __builtin_amdgcn_mfma_f32_16x16x32_f16(a, b1, acc1, 0, 0, 0);
      acc2 = __builtin_amdgcn_mfma_f32_16x16x32_f16(a, b2, acc2, 0, 0, 0);
      acc3 = __builtin_amdgcn_mfma_f32_16x16x32_f16(a, b3, acc3, 0, 0, 0);
    }
    // C/D: col(cis16) = lane&15, row(b) = (lane>>4)*4 + reg; rows 0..3 in lanes 0..15
    if (l < 16) {
#pragma unroll
      for (int r = 0; r < 4; ++r) {
        gsm[r][(w * 4 + 0) * 16 + l] = acc0[r];
        gsm[r][(w * 4 + 1) * 16 + l] = acc1[r];
        gsm[r][(w * 4 + 2) * 16 + l] = acc2[r];
        gsm[r][(w * 4 + 3) * 16 + l] = acc3[r];
      }
    }
    __syncthreads();   // B1: gsm ready; all h_frag reads of step t done

    {
      const float gi = gsm[b_loc][j] + __half2float(rxi);
      const float gf = gsm[b_loc][32 + j] + __half2float(rxf);
      const float go = gsm[b_loc][64 + j] + __half2float(rxo);
      const float gu = gsm[b_loc][96 + j] + __half2float(rxu);
      const float iv = fast_sigmoid(gi);
      const float fv = fast_sigmoid(gf);
      const float ov = fast_sigmoid(go);
      const float uv = fast_tanh(gu);
      c_reg = fv * c_reg + iv * uv;
      h_reg = ov * fast_tanh(c_reg);
    }

    const int slot = (t + 1) & 1;
    const unsigned tg = (unsigned)((tbase + t + 1) & 0xffff);
    {
      const unsigned short hb =
          __builtin_bit_cast(unsigned short, __float2half(h_reg));
      __hip_atomic_store(&hx[slot * 32768 + b_glob * 512 + s * 32 + j],
                         (tg << 16) | (unsigned)hb,
                         __ATOMIC_RELAXED, __HIP_MEMORY_SCOPE_AGENT);
    }
    out[((size_t)t * BB + b_glob) * HH + s * 32 + j] = h_reg;

    if (t + 1 < nsteps) {
      // prefetch x(t+1): issued before the poll, completes under the spin
      const __half* xb = xall + ((size_t)(t + 1) * BB + b_glob) * NG + s * 32 + j;
      rxi = xb[0]; rxf = xb[512]; rxo = xb[1024]; rxu = xb[1536];

      const unsigned* src = hx + slot * 32768 + (size_t)(g * BSZ + r5) * 512 + w5 * 16;
      unsigned vals[16];
      if (!dead) {
        int it = 0;
        for (;;) {
          bool ok = true;
#pragma unroll
          for (int e = 0; e < 16; ++e)
            vals[e] = __hip_atomic_load(&src[e], __ATOMIC_RELAXED,
                                        __HIP_MEMORY_SCOPE_AGENT);
#pragma unroll
          for (int e = 0; e < 16; ++e) ok &= ((vals[e] >> 16) == tg);
          if (ok) break;
          if (dead) break;
          if (++it > 8192) { dead = 1; break; }   // bounded: no hang
          __builtin_amdgcn_s_sleep(2);
        }
      } else {
#pragma unroll
        for (int e = 0; e < 16; ++e)
          vals[e] = __hip_atomic_load(&src[e], __ATOMIC_RELAXED,
                                      __HIP_MEMORY_SCOPE_AGENT);
      }
      unsigned d[8];
#pragma unroll
      for (int p = 0; p < 8; ++p)
        d[p] = (vals[2 * p] & 0xffffu) | (vals[2 * p + 1] << 16);
      *(uint4*)&h_frag[hoff] = ((const uint4*)d)[0];
      *(uint4*)&h_frag[hoff + 128] = ((const uint4*)d)[1];
      __syncthreads();   // B2: h_frag(t+1) ready; gsm reads done
    }
  }

  h_out[(size_t)b_glob * HH + s * 32 + j] = h_reg;
  c_out[(size_t)b_glob * HH + s * 32 + j] = c_reg;
}

// ---------------- launch ----------------

extern "C" void kernel_launch(void* const* d_in, const int* in_sizes, int n_in,
                              void* d_out, int out_size, void* d_ws, size_t ws_size,
                              hipStream_t stream) {
  const float* inputs = (const float*)d_in[0];
  const float* h0     = (const float*)d_in[1];
  const float* c0v    = (const float*)d_in[2];
  const float* Wxi    = (const float*)d_in[3];
  const float* Whi    = (const float*)d_in[4];
  const float* Wxf    = (const float*)d_in[5];
  const float* Whf    = (const float*)d_in[6];
  const float* Wxu    = (const float*)d_in[7];
  const float* Whu    = (const float*)d_in[8];
  const float* Wxo    = (const float*)d_in[9];
  const float* Who    = (const float*)d_in[10];
  const float* bi     = (const float*)d_in[11];
  const float* bf     = (const float*)d_in[12];
  const float* bo     = (const float*)d_in[13];
  const float* bu     = (const float*)d_in[14];

  const size_t BIAS_BYTES = (size_t)NG * 4;                    // 8 KiB
  const size_t WPK_BYTES  = (size_t)131072 * 16;               // 2 MiB
  const size_t WXPK_BYTES = (size_t)131072 * 16;               // 2 MiB
  const size_t ST_BYTES   = (size_t)BB * HH * 4;               // 128 KiB
  const size_t HX_BYTES   = (size_t)2 * BB * HH * 4;           // 256 KiB
  const size_t FIXED = BIAS_BYTES + WPK_BYTES + WXPK_BYTES + 2 * ST_BYTES + HX_BYTES;
  // per timestep: Axpk f16 (64*512*2) + xall f16 (64*2048*2)
  const size_t PER_T = (size_t)BB * II * 2 + (size_t)BB * NG * 2;

  int TCH = TT;
  while (TCH > 8 && FIXED + (size_t)TCH * PER_T > ws_size) TCH >>= 1;
  int mshift = 0;
  while ((1 << mshift) < TCH) ++mshift;          // TCH power of 2

  char* ws = (char*)d_ws;
  float*    bias    = (float*)ws;
  uint4*    Wpk     = (uint4*)(ws + BIAS_BYTES);
  uint4*    Wxpk    = (uint4*)(ws + BIAS_BYTES + WPK_BYTES);
  float*    h_state = (float*)(ws + BIAS_BYTES + WPK_BYTES + WXPK_BYTES);
  float*    c_state = (float*)(ws + BIAS_BYTES + WPK_BYTES + WXPK_BYTES + ST_BYTES);
  unsigned* hx      = (unsigned*)(ws + BIAS_BYTES + WPK_BYTES + WXPK_BYTES + 2 * ST_BYTES);
  uint4*    Axpk    = (uint4*)(ws + FIXED);
  __half*   xall    = (__half*)(ws + FIXED + (size_t)TCH * BB * II * 2);

  float* out = (float*)d_out;
  float* hT  = out + (size_t)TT * BB * HH;
  float* cT  = hT + (size_t)BB * HH;

  prep_bias<<<NG / 256, 256, 0, stream>>>(bi, bf, bo, bu, bias);
  prep_wpk<<<512, 256, 0, stream>>>(Whi, Whf, Who, Whu, Wpk);
  prep_wxpk<<<512, 256, 0, stream>>>(Wxi, Wxf, Wxo, Wxu, Wxpk);

  const int nch = TT / TCH;
  for (int ch = 0; ch < nch; ++ch) {
    const int t0 = ch * TCH;
    prep_axpk<<<(TCH * BB * 64) / 256, 256, 0, stream>>>(
        inputs + (size_t)t0 * BB * II, Axpk);
    gemm_x<<<TCH * 8, 256, 0, stream>>>(Axpk, Wxpk, bias, xall, mshift);

    const float* hin = (ch == 0) ? h0 : h_state;
    const float* cin = (ch == 0) ? c0v : c_state;
    float* hout = (ch == nch - 1) ? hT : h_state;
    float* cout = (ch == nch - 1) ? cT : c_state;
    lstm_rec<<<NSL * NGR, 128, 0, stream>>>(Wpk, xall, hin, cin,
                                            out + (size_t)t0 * BB * HH, hout, cout,
                                            hx, TCH, t0);
  }
}